// Round 6
// baseline (369.230 us; speedup 1.0000x reference)
//
#include <hip/hip_runtime.h>

typedef unsigned short u16;
typedef __bf16 bf16x8 __attribute__((ext_vector_type(8)));
typedef float  f32x4  __attribute__((ext_vector_type(4)));

#define SEQ 2048

__device__ __forceinline__ float bf2f(u16 u) {
    union { unsigned int i; float f; } c;
    c.i = ((unsigned int)u) << 16;
    return c.f;
}
__device__ __forceinline__ u16 f2bf(float f) {
    union { float f; unsigned int i; } c;
    c.f = f;
    unsigned int u = c.i;
    u += 0x7FFFu + ((u >> 16) & 1u);   // round-to-nearest-even
    return (u16)(u >> 16);
}

// async global->LDS, 16B per lane; lds dest = wave-uniform base + lane*16
__device__ __forceinline__ void gl_lds16(const u16* g, u16* l) {
    __builtin_amdgcn_global_load_lds(
        (const __attribute__((address_space(1))) unsigned int*)(g),
        (__attribute__((address_space(3))) unsigned int*)(l), 16, 0, 0);
}

__device__ __forceinline__ void cvt4(const float* s, u16* d) {
    float4 v = *(const float4*)s;
    ushort4 o;
    o.x = f2bf(v.x); o.y = f2bf(v.y); o.z = f2bf(v.z); o.w = f2bf(v.w);
    *(ushort4*)d = o;
}

// ---------------------------------------------------------------- fused prep
__global__ void prep(const float* __restrict__ x,
                     const float* __restrict__ wq, const float* __restrict__ wk,
                     const float* __restrict__ wv,
                     const float* __restrict__ bq, const float* __restrict__ bk,
                     const float* __restrict__ bv,
                     u16* __restrict__ xb, u16* __restrict__ wqkvb,
                     float* __restrict__ biasb)
{
    const int E0 = 2097152;            // x float4s
    const int E1 = E0 + 1048576;       // wq
    const int E2 = E1 + 262144;        // wk
    const int E3 = E2 + 262144;        // wv
    const int E4 = E3 + 768;           // bias float4s
    int i = blockIdx.x * blockDim.x + threadIdx.x;
    int stride = gridDim.x * blockDim.x;
    for (; i < E4; i += stride) {
        if (i < E0)      cvt4(x  + (size_t)i * 4,        xb    + (size_t)i * 4);
        else if (i < E1) cvt4(wq + (size_t)(i - E0) * 4, wqkvb + (size_t)(i - E0) * 4);
        else if (i < E2) cvt4(wk + (size_t)(i - E1) * 4, wqkvb + 4194304 + (size_t)(i - E1) * 4);
        else if (i < E3) cvt4(wv + (size_t)(i - E2) * 4, wqkvb + 5242880 + (size_t)(i - E2) * 4);
        else {
            int j = i - E3;            // 0..767
            const float* src = (j < 512) ? (bq + j * 4)
                             : (j < 640) ? (bk + (j - 512) * 4)
                                         : (bv + (j - 640) * 4);
            *(float4*)&biasb[j * 4] = *(const float4*)src;
        }
    }
}

__global__ void cvt_f32_bf16(const float* __restrict__ in, u16* __restrict__ out, int n4) {
    int i = blockIdx.x * blockDim.x + threadIdx.x;
    int stride = gridDim.x * blockDim.x;
    for (; i < n4; i += stride) cvt4(in + (size_t)i * 4, out + (size_t)i * 4);
}

// ---------------------------------------------------------------- GEMM C = A*B^T + bias
// BK=64 (2 sub-steps per barrier pair), dual 32-col LDS panels (r5's proven frag pattern).
// MODE 0: C fp32. MODE 1: qkv split q/k natural (B,H,S,128), v transposed (B,4,128,S).
template<int MODE>
__global__ __launch_bounds__(256) void gemm_bt(
    const u16* __restrict__ A, const u16* __restrict__ B,
    const float* __restrict__ bias, float* __restrict__ C,
    u16* __restrict__ qb, u16* __restrict__ kb, u16* __restrict__ vt,
    int M, int N, int K)
{
    __shared__ __align__(16) u16 lA[2][128][32];   // 16KB: [k-half][row][32]
    __shared__ __align__(16) u16 lB[2][128][32];
    const int tid   = threadIdx.x;
    const int lane  = tid & 63;
    const int wave  = tid >> 6;
    const int waveM = (wave >> 1) * 64;
    const int waveN = (wave & 1) * 64;
    const int bm = blockIdx.x * 128;
    const int bn = blockIdx.y * 128;
    const int lrow = lane & 15;
    const int koff = (lane >> 4) * 8;

    // staging source offsets (u16 units into the 128x64 tile), decoded from the
    // physical LDS slot o = id*16 bytes, id = p*256 + tid
    int asrc[4];
#pragma unroll
    for (int p = 0; p < 4; ++p) {
        int o   = (p * 256 + tid) * 16;     // byte offset in 16KB buffer
        int pan = o >> 13;                  // k-half panel
        int r   = (o >> 6) & 127;           // row
        int c   = (o >> 4) & 3;             // 16B chunk in 64B row
        asrc[p] = r * K + pan * 32 + c * 8; // note: *K row stride (runtime)
    }

    f32x4 acc[4][4] = {};

    for (int k0 = 0; k0 < K; k0 += 64) {
        __syncthreads();
#pragma unroll
        for (int p = 0; p < 4; ++p) {
            gl_lds16(&A[(size_t)bm * K + k0 + asrc[p]], &lA[0][0][0] + (p * 256 + wave * 64) * 8);
            gl_lds16(&B[(size_t)bn * K + k0 + asrc[p]], &lB[0][0][0] + (p * 256 + wave * 64) * 8);
        }
        __syncthreads();

#pragma unroll
        for (int s = 0; s < 2; ++s) {
            bf16x8 af[4], bfr[4];
#pragma unroll
            for (int i = 0; i < 4; ++i)
                af[i] = *(const bf16x8*)&lA[s][waveM + i * 16 + lrow][koff];
#pragma unroll
            for (int j = 0; j < 4; ++j)
                bfr[j] = *(const bf16x8*)&lB[s][waveN + j * 16 + lrow][koff];
#pragma unroll
            for (int i = 0; i < 4; ++i)
#pragma unroll
                for (int j = 0; j < 4; ++j)
                    acc[i][j] = __builtin_amdgcn_mfma_f32_16x16x32_bf16(
                        af[i], bfr[j], acc[i][j], 0, 0, 0);
        }
    }

    const int r4 = (lane >> 4) * 4;
    const int cn = lane & 15;
#pragma unroll
    for (int i = 0; i < 4; ++i) {
#pragma unroll
        for (int j = 0; j < 4; ++j) {
            int row0 = bm + waveM + i * 16 + r4;
            int col  = bn + waveN + j * 16 + cn;
            float bc = bias[col];
#pragma unroll
            for (int r = 0; r < 4; ++r) {
                float val = acc[i][j][r] + bc;
                if (MODE == 0) {
                    C[(size_t)(row0 + r) * N + col] = val;
                } else {
                    int row = row0 + r;
                    int b = row >> 11;          // row = b*2048 + s
                    int s = row & 2047;
                    int d = col & 127;
                    u16 o = f2bf(val);
                    if (col < 2048) {
                        int h = col >> 7;
                        qb[(((size_t)(b * 16 + h) * SEQ) + s) * 128 + d] = o;
                    } else if (col < 2560) {
                        int h = (col - 2048) >> 7;
                        kb[(((size_t)(b * 4 + h) * SEQ) + s) * 128 + d] = o;
                    } else {
                        int h = (col - 2560) >> 7;
                        vt[(((size_t)(b * 4 + h) * 128) + d) * SEQ + s] = o;  // V^T
                    }
                }
            }
        }
    }
}

// ---------------------------------------------------------------- RoPE in-place on K only
// (Q-RoPE is fused into attn's register Q-load.)
__global__ void rope_k(u16* __restrict__ kb,
                       const float* __restrict__ cosb, const float* __restrict__ sinb)
{
    const int n = 16384 * 64;          // 2*4*2048 rows x 64 pairs
    int i = blockIdx.x * blockDim.x + threadIdx.x;
    if (i >= n) return;
    int d0  = i & 63;
    int row = i >> 6;
    u16* base = kb + (size_t)row * 128;
    int s = row & (SEQ - 1);
    float c  = cosb[s * 128 + d0];
    float sn = sinb[s * 128 + d0];
    float a0 = bf2f(base[d0]);
    float a1 = bf2f(base[d0 + 64]);
    base[d0]      = f2bf(a0 * c - a1 * sn);
    base[d0 + 64] = f2bf(a1 * c + a0 * sn);
}

// ---------------------------------------------------------------- MFMA flash attention v4
// grid (32 [qt, reversed], 16 [h], 2 [b]) = 1024 blocks; 256 threads; 40KB LDS -> 4 blocks/CU.
// One 64-row q-tile per block; K-tiles of 64. Single-buffered staging (2 barriers/tile;
// 16 waves/CU co-residency hides the drain). No-max exp2 softmax. Q-RoPE fused in load.
__global__ __launch_bounds__(256, 4) void attn_mfma(
    const u16* __restrict__ qb, const u16* __restrict__ kb,
    const u16* __restrict__ vt, u16* __restrict__ ob,
    const float* __restrict__ cosb, const float* __restrict__ sinb)
{
    __shared__ __align__(16) u16 Ks[4][64][32];    // 16KB: [d-chunk][kcol][32]
    __shared__ __align__(16) u16 Vts[2][128][32];  // 16KB: [kcol-half][d][32]
    __shared__ __align__(16) u16 Ph[4][16][64];    // 8KB: per-wave rot-swizzled P

    const int qt   = 31 - blockIdx.x;              // big blocks dispatch first
    const int h    = blockIdx.y;
    const int b    = blockIdx.z;
    const int kvh  = h >> 2;
    const int tid  = threadIdx.x;
    const int lane = tid & 63;
    const int w    = tid >> 6;
    const int c16  = lane & 15;
    const int quad = lane >> 4;
    const float qscale = 0.08838834764831845f * 1.4426950408889634f; // 1/sqrt(128)*log2(e)

    const u16* kbase  = kb + ((size_t)(b * 4 + kvh) * SEQ) * 128;
    const u16* vtbase = vt + ((size_t)(b * 4 + kvh) * 128) * SEQ;

    // Q A-frags: load raw, apply RoPE in-register (pairs d,d+64 are frags kk,kk+2
    // of the same lane), pre-scale, convert once.
    const int s_row = qt * 64 + w * 16 + c16;
    bf16x8 qf[4];
    {
        const u16* qp = qb + (((size_t)(b * 16 + h)) * SEQ + s_row) * 128;
        bf16x8 rq[4];
#pragma unroll
        for (int kk = 0; kk < 4; ++kk)
            rq[kk] = *(const bf16x8*)(qp + kk * 32 + quad * 8);
#pragma unroll
        for (int kk = 0; kk < 2; ++kk) {
            const float* cb = cosb + s_row * 128 + kk * 32 + quad * 8;
            const float* sb = sinb + s_row * 128 + kk * 32 + quad * 8;
            float4 c0 = *(const float4*)cb, c1 = *(const float4*)(cb + 4);
            float4 s0 = *(const float4*)sb, s1 = *(const float4*)(sb + 4);
            float cc[8] = {c0.x, c0.y, c0.z, c0.w, c1.x, c1.y, c1.z, c1.w};
            float ss[8] = {s0.x, s0.y, s0.z, s0.w, s1.x, s1.y, s1.z, s1.w};
#pragma unroll
            for (int e = 0; e < 8; ++e) {
                float a0 = (float)rq[kk][e];
                float a1 = (float)rq[kk + 2][e];
                qf[kk][e]     = (__bf16)((a0 * cc[e] - a1 * ss[e]) * qscale);
                qf[kk + 2][e] = (__bf16)((a1 * cc[e] + a0 * ss[e]) * qscale);
            }
        }
    }

    // staging source offsets (u16 units into the tile); 16KB per buffer, 4 chunks/thread
    int ksrc[4], vsrc[4];
#pragma unroll
    for (int it = 0; it < 4; ++it) {
        int o  = (it * 4 + w) * 1024 + lane * 16;  // physical byte offset in 16KB region
        {   // K: panels [kk=d/32][kcol 64][32]
            int kk = o >> 12;
            int r  = (o >> 6) & 63;
            int c  = (o >> 4) & 3;
            ksrc[it] = r * 128 + kk * 32 + c * 8;
        }
        {   // V^T: panels [k2=kcol/32][d 128][32]
            int k2 = o >> 13;
            int d  = (o >> 6) & 127;
            int c  = (o >> 4) & 3;
            vsrc[it] = d * SEQ + k2 * 32 + c * 8;
        }
    }

    const int rowL = qt * 64 + w * 16 + quad * 4;
    f32x4 o_acc[8] = {};
    float l_r[4] = {};

    for (int kt = 0; kt <= qt; ++kt) {
        __syncthreads();                           // all waves done with prev K/V
        const u16* kg = kbase + (size_t)kt * (64 * 128);
        const u16* vg = vtbase + kt * 64;
#pragma unroll
        for (int it = 0; it < 4; ++it) {
            gl_lds16(kg + ksrc[it], &Ks[0][0][0]  + (it * 4 + w) * 512);
            gl_lds16(vg + vsrc[it], &Vts[0][0][0] + (it * 4 + w) * 512);
        }
        __syncthreads();                           // drains DMA

        // S = Q K^T  (16 MFMAs, 16 kf reads)
        f32x4 s_acc[4] = {};
#pragma unroll
        for (int kk = 0; kk < 4; ++kk)
#pragma unroll
            for (int j = 0; j < 4; ++j) {
                bf16x8 kf = *(const bf16x8*)&Ks[kk][j * 16 + c16][quad * 8];
                s_acc[j] = __builtin_amdgcn_mfma_f32_16x16x32_bf16(qf[kk], kf, s_acc[j], 0, 0, 0);
            }

        if (kt == qt) {                            // causal mask, diagonal tile only
#pragma unroll
            for (int j = 0; j < 4; ++j)
#pragma unroll
                for (int rr = 0; rr < 4; ++rr)
                    if (j * 16 + c16 > w * 16 + quad * 4 + rr) s_acc[j][rr] = -1e30f;
        }

        // exp2 -> P (rot-swizzled per-wave LDS) -> A-frags
#pragma unroll
        for (int j = 0; j < 4; ++j)
#pragma unroll
            for (int rr = 0; rr < 4; ++rr) {
                float p = __builtin_amdgcn_exp2f(s_acc[j][rr]);
                l_r[rr] += p;
                int row = quad * 4 + rr;
                Ph[w][row][(((j * 2 + (c16 >> 3)) + row) & 7) * 8 + (c16 & 7)] = f2bf(p);
            }
        bf16x8 pa[2];
#pragma unroll
        for (int k2 = 0; k2 < 2; ++k2)
            pa[k2] = *(const bf16x8*)&Ph[w][c16][(((k2 * 4 + quad) + c16) & 7) * 8];

        // O += P V  (16 MFMAs, 16 vf reads)
#pragma unroll
        for (int k2 = 0; k2 < 2; ++k2)
#pragma unroll
            for (int nt = 0; nt < 8; ++nt) {
                bf16x8 vf = *(const bf16x8*)&Vts[k2][nt * 16 + c16][quad * 8];
                o_acc[nt] = __builtin_amdgcn_mfma_f32_16x16x32_bf16(pa[k2], vf, o_acc[nt], 0, 0, 0);
            }
    }

    // epilogue: row-sum of l across the 16-lane col groups, normalize, store
    float linv[4];
#pragma unroll
    for (int rr = 0; rr < 4; ++rr) {
        float l = l_r[rr];
        l += __shfl_xor(l, 1);
        l += __shfl_xor(l, 2);
        l += __shfl_xor(l, 4);
        l += __shfl_xor(l, 8);
        linv[rr] = 1.0f / l;
    }
    const size_t rowG = (size_t)b * SEQ + rowL;
#pragma unroll
    for (int nt = 0; nt < 8; ++nt)
#pragma unroll
        for (int rr = 0; rr < 4; ++rr)
            ob[(rowG + rr) * 2048 + h * 128 + nt * 16 + c16] = f2bf(o_acc[nt][rr] * linv[rr]);
}

// ---------------------------------------------------------------- launch
extern "C" void kernel_launch(void* const* d_in, const int* in_sizes, int n_in,
                              void* d_out, int out_size, void* d_ws, size_t ws_size,
                              hipStream_t stream) {
    const float* x    = (const float*)d_in[0];
    const float* wq   = (const float*)d_in[1];
    const float* bq   = (const float*)d_in[2];
    const float* wk   = (const float*)d_in[3];
    const float* bk   = (const float*)d_in[4];
    const float* wv   = (const float*)d_in[5];
    const float* bv   = (const float*)d_in[6];
    const float* wo   = (const float*)d_in[7];
    const float* bo   = (const float*)d_in[8];
    const float* cosb = (const float*)d_in[9];
    const float* sinb = (const float*)d_in[10];
    float* out = (float*)d_out;

    char* ws = (char*)d_ws;
    // workspace layout (bytes); total ~52 MB (validated r2-r5)
    const size_t OFF_WQKV = 0;              // 12,582,912  packed [wq|wk|wv] bf16; later wo bf16
    const size_t OFF_BIAS = 12582912;       //     16,384  packed qkv bias f32
    const size_t OFF_QB   = 12599296;       // 16,777,216  q bf16 (B,16,S,128)
    const size_t OFF_KB   = 29376512;       //  4,194,304  k bf16 (B,4,S,128)
    const size_t OFF_VT   = 33570816;       //  4,194,304  v^T bf16 (B,4,128,S)
    const size_t OFF_XB   = 37765120;       // 16,777,216  x bf16; later attn out bf16

    u16*   wqkvb = (u16*)(ws + OFF_WQKV);
    u16*   wob   = (u16*)(ws + OFF_WQKV);   // reuse after GEMM1
    float* biasb = (float*)(ws + OFF_BIAS);
    u16*   qb2   = (u16*)(ws + OFF_QB);
    u16*   kb2   = (u16*)(ws + OFF_KB);
    u16*   vt2   = (u16*)(ws + OFF_VT);
    u16*   xb    = (u16*)(ws + OFF_XB);
    u16*   attnb = (u16*)(ws + OFF_XB);     // reuse after GEMM1

    // 1. fused prep: x->bf16, wq/wk/wv->bf16 packed, bias pack
    prep<<<4096, 256, 0, stream>>>(x, wq, wk, wv, bq, bk, bv, xb, wqkvb, biasb);

    // 2. qkv = x @ [wq|wk|wv]^T + bias, split-written bf16: q,k natural; v transposed
    gemm_bt<1><<<dim3(32, 24), 256, 0, stream>>>(xb, wqkvb, biasb, nullptr,
                                                 qb2, kb2, vt2, 4096, 3072, 2048);

    // 3. wo -> bf16 (reuses wqkv region; stream-ordered after GEMM1)
    cvt_f32_bf16<<<4096, 256, 0, stream>>>(wo, wob, 1048576);

    // 4. RoPE in-place on K only (Q-rope fused into attn)
    rope_k<<<(16384 * 64) / 256, 256, 0, stream>>>(kb2, cosb, sinb);

    // 5. causal GQA MFMA attention v4 -> (B*S, 2048) bf16
    attn_mfma<<<dim3(32, 16, 2), 256, 0, stream>>>(qb2, kb2, vt2, attnb, cosb, sinb);

    // 6. out = attn @ wo^T + bo  (fp32 to d_out)
    gemm_bt<0><<<dim3(32, 16), 256, 0, stream>>>(attnb, wob, bo, out,
                                                 nullptr, nullptr, nullptr, 4096, 2048, 2048);
}